// Round 7
// baseline (102.596 us; speedup 1.0000x reference)
//
#include <hip/hip_runtime.h>
#include <math.h>

#define KCOMP 8
#define DDIM  16

typedef __attribute__((ext_vector_type(8))) short bf16x8;
typedef __attribute__((ext_vector_type(4))) float f32x4;

// fp32 -> bf16 bits, round-to-nearest-even (used in prep only; one-time cost)
static __device__ __forceinline__ unsigned short f2bf_rne(float f) {
    unsigned u = __float_as_uint(f);
    unsigned r = (u + 0x7FFFu + ((u >> 16) & 1u)) >> 16;
    return (unsigned short)r;
}

// Fully fused kernel, round-6 register discipline (the round-5 fusion failed
// on pk[4][8] scratch spills + 512-block grid; both fixed here).
//
// Phase 1 (threads 0..127 = 8 groups x 16 lanes): shuffle Cholesky of sigma_k,
//   forward-substitution L^-1, then emit a PACKED bf16 A-fragment table to LDS
//   (one bf16x8 per (k,lane), 8 KB) + ck[] = log pi_k - logdet_k - D/2 log2pi.
//   A-fragment semantics (mfma_f32_16x16x32_bf16, A[m=lane&15][kk=quad*8+j]):
//     quad 0/1: Linv_k[m][quad*8+j]; quad 2,j==0: -b_k[m] (kk=16); else 0.
//
// Phase 2 (all 4 waves, 64 samples each): A from LDS (8 x ds_read_b128),
//   B = z~^T per 16-sample tile (z rows in quads 0/1 via truncating cvt,
//   bf16(1.0) bias at kk=16). D: col=lane&15 (sample), row=quad*4+reg.
//   maha via 2 shfl_xor; quad-select BEFORE the LSE -> each lane does one
//   8-way log-sum-exp for its own sample. No LDS in the k-loop, no arrays
//   beyond lp[8]/afrag[8]/bfrag[4].
__global__ __launch_bounds__(256, 4) void dagmm_kernel(
    const float* __restrict__ mu, const float* __restrict__ sigma,
    const float* __restrict__ pi, const float* __restrict__ z,
    float* __restrict__ out, int n)
{
    __shared__ uint4 sAfrag[KCOMP * 64];   // packed bf16x8 per (k, lane)
    __shared__ float sC[KCOMP];

    const int tid = threadIdx.x;

    // ---------------- Phase 1: prep (threads 0..127) ----------------------
    if (tid < 128) {
        const int g = tid >> 4;   // component
        const int r = tid & 15;   // row (cholesky) / column (inverse)

        float a[DDIM];
        const float4* srow = (const float4*)(sigma + g * DDIM * DDIM + r * DDIM);
        float4 v0 = srow[0], v1 = srow[1], v2 = srow[2], v3 = srow[3];
        a[0]=v0.x;  a[1]=v0.y;  a[2]=v0.z;  a[3]=v0.w;
        a[4]=v1.x;  a[5]=v1.y;  a[6]=v1.z;  a[7]=v1.w;
        a[8]=v2.x;  a[9]=v2.y;  a[10]=v2.z; a[11]=v2.w;
        a[12]=v3.x; a[13]=v3.y; a[14]=v3.z; a[15]=v3.w;

        // Cholesky: lane r computes row r of L via width-16 shuffles.
        float l[DDIM];
        #pragma unroll
        for (int j = 0; j < DDIM; ++j) {
            float s = a[j];
            #pragma unroll
            for (int m2 = 0; m2 < j; ++m2)
                s -= l[m2] * __shfl(l[m2], j, DDIM);
            float dj = sqrtf(__shfl(s, j, DDIM));
            float val;
            if (r == j)      val = dj;
            else if (r > j)  val = s / dj;
            else             val = 0.0f;
            l[j] = val;
        }

        // Invert L: lane r computes column r of Linv (forward substitution).
        float x[DDIM];
        #pragma unroll
        for (int i = 0; i < DDIM; ++i) {
            float t = (r == i) ? 1.0f : 0.0f;
            #pragma unroll
            for (int m2 = 0; m2 < i; ++m2)
                t -= __shfl(l[m2], i, DDIM) * x[m2];
            x[i] = t / __shfl(l[i], i, DDIM);
        }
        // Lane r holds COLUMN r of Linv: x[i] = Linv[i][r].

        // b_r = (Linv . mu)[r] = sum_c Linv[r][c] mu[c]; lane r holds column r,
        // so compute via shuffle: Linv[r][c] = shfl(x[r-as-index? no]) --
        // simpler: each lane computes b for ITS row r: Linv[r][c] = x_c's
        // lane-c value of x[r] -> b_r = sum_c shfl(x[r], c) * mu[c].
        float b = 0.0f;
        #pragma unroll
        for (int c = 0; c < DDIM; ++c)
            b += __shfl(x[r], c, DDIM) * mu[g * DDIM + c];
        // (x[r] in lane c is Linv[r][c])

        // logdet = sum_r log(L_rr)
        float ld = logf(l[r]);
        #pragma unroll
        for (int off = 8; off >= 1; off >>= 1)
            ld += __shfl_xor(ld, off, DDIM);
        if (r == 0) {
            const float LOG2PI = 1.8378770664093454f;
            sC[g] = logf(pi[g]) - ld - 0.5f * DDIM * LOG2PI;
        }

        // Emit packed afrag entries for this component: entries (g, lane
        // 0..63). Each of the 16 lanes in the group emits 4 entries
        // (one per quad), for lane index quad*16 + m with m = r.
        // quad 0: Linv[m][0..7], quad 1: Linv[m][8..15], quad 2: {-b_m,0..},
        // quad 3: zeros. Lane r holds column r (x[i] = Linv[i][r]) -> row m
        // values come via shuffle: Linv[m][c] = shfl(x[m], c).
        #pragma unroll
        for (int quad = 0; quad < 4; ++quad) {
            float vals[8];
            #pragma unroll
            for (int j = 0; j < 8; ++j) {
                int c = quad * 8 + j;
                float lv = (quad < 2) ? __shfl(x[r], c, DDIM) : 0.0f;
                if (quad == 2 && j == 0) lv = -b;
                vals[j] = lv;
            }
            uint4 p;
            p.x = (unsigned)f2bf_rne(vals[0]) | ((unsigned)f2bf_rne(vals[1]) << 16);
            p.y = (unsigned)f2bf_rne(vals[2]) | ((unsigned)f2bf_rne(vals[3]) << 16);
            p.z = (unsigned)f2bf_rne(vals[4]) | ((unsigned)f2bf_rne(vals[5]) << 16);
            p.w = (unsigned)f2bf_rne(vals[6]) | ((unsigned)f2bf_rne(vals[7]) << 16);
            sAfrag[g * 64 + quad * 16 + r] = p;
        }
    }
    __syncthreads();

    // ---------------- Phase 2: MFMA scoring (all 4 waves) -----------------
    const int lane = tid & 63;
    const int m    = lane & 15;
    const int quad = lane >> 4;
    const int base = ((blockIdx.x * 256 + tid) >> 6) * 64;   // 64 samples/wave

    // A fragments: 8 x ds_read_b128
    bf16x8 afrag[KCOMP];
    #pragma unroll
    for (int k = 0; k < KCOMP; ++k)
        afrag[k] = ((const bf16x8*)sAfrag)[k * 64 + lane];

    float ck[KCOMP];
    #pragma unroll
    for (int k = 0; k < KCOMP; ++k) ck[k] = sC[k];   // LDS broadcast

    // Prefetch all 4 z-tiles; truncating fp32->bf16 (1 op/elem; finite
    // inputs can't become NaN, and the tiny extra rounding error is far
    // below the test's tolerance).
    bf16x8 bfrag[4];
    #pragma unroll
    for (int t = 0; t < 4; ++t) {
        bf16x8 bf = {0,0,0,0,0,0,0,0};
        const int s = base + t * 16 + m;
        if (quad < 2) {
            if (s < n) {
                const float4* zp = (const float4*)(z + (size_t)s * DDIM + quad * 8);
                float4 w0 = zp[0], w1 = zp[1];
                bf[0]=(short)(__float_as_uint(w0.x) >> 16);
                bf[1]=(short)(__float_as_uint(w0.y) >> 16);
                bf[2]=(short)(__float_as_uint(w0.z) >> 16);
                bf[3]=(short)(__float_as_uint(w0.w) >> 16);
                bf[4]=(short)(__float_as_uint(w1.x) >> 16);
                bf[5]=(short)(__float_as_uint(w1.y) >> 16);
                bf[6]=(short)(__float_as_uint(w1.z) >> 16);
                bf[7]=(short)(__float_as_uint(w1.w) >> 16);
            }
        } else if (quad == 2) {
            bf[0] = (short)0x3F80;   // bf16(1.0) bias row (kk = 16)
        }
        bfrag[t] = bf;
    }

    const f32x4 zero4 = {0.f, 0.f, 0.f, 0.f};
    float lp[KCOMP];

    #pragma unroll
    for (int t = 0; t < 4; ++t) {
        #pragma unroll
        for (int k = 0; k < KCOMP; ++k) {
            f32x4 d4 = __builtin_amdgcn_mfma_f32_16x16x32_bf16(
                           afrag[k], bfrag[t], zero4, 0, 0, 0);
            float p = d4[0]*d4[0] + d4[1]*d4[1] + d4[2]*d4[2] + d4[3]*d4[3];
            p += __shfl_xor(p, 16, 64);
            p += __shfl_xor(p, 32, 64);          // all lanes: maha of tile t, col m
            float lpv = fmaf(-0.5f, p, ck[k]);
            if (t == 0) lp[k] = lpv;             // each lane keeps its quad's tile
            else        lp[k] = (quad == t) ? lpv : lp[k];
        }
    }

    // 8-component log-sum-exp for this lane's sample (base + lane)
    float mx = lp[0];
    #pragma unroll
    for (int k = 1; k < KCOMP; ++k) mx = fmaxf(mx, lp[k]);
    float dens = 0.0f;
    #pragma unroll
    for (int k = 0; k < KCOMP; ++k) dens += __expf(lp[k] - mx);

    const int so = base + lane;
    if (so < n) out[so] = -(mx + __logf(dens));
}

extern "C" void kernel_launch(void* const* d_in, const int* in_sizes, int n_in,
                              void* d_out, int out_size, void* d_ws, size_t ws_size,
                              hipStream_t stream) {
    const float* mu    = (const float*)d_in[0];
    const float* sigma = (const float*)d_in[1];
    const float* z     = (const float*)d_in[2];
    const float* pi    = (const float*)d_in[3];
    float* out = (float*)d_out;
    (void)d_ws; (void)ws_size;

    const int n = in_sizes[2] / DDIM;   // number of samples (524288)

    // 64 samples/wave, 4 waves/block -> 256 samples/block; 2048 blocks
    const int blocks = (n + 255) / 256;
    dagmm_kernel<<<blocks, 256, 0, stream>>>(mu, sigma, pi, z, out, n);
}

// Round 8
// 95.789 us; speedup vs baseline: 1.0711x; 1.0711x over previous
//
#include <hip/hip_runtime.h>
#include <math.h>

#define KCOMP 8
#define DDIM  16

typedef __attribute__((ext_vector_type(8))) short bf16x8;
typedef __attribute__((ext_vector_type(4))) float f32x4;

// fp32 -> bf16 bits, round-to-nearest-even (prep only; one-time cost)
static __device__ __forceinline__ unsigned short f2bf(float f) {
    unsigned u = __float_as_uint(f);
    unsigned r = (u + 0x7FFFu + ((u >> 16) & 1u)) >> 16;
    return (unsigned short)r;
}

// ws layout:
//   bytes [0, 8192)      afrag table: entry e = k*64 + lane, 16 B each
//                        (8 bf16 = the lane's A-fragment for component k)
//   floats [2048, 2056)  ck[k] = log(pi_k) - logdet_k - D/2 log 2pi
//
// A-fragment semantics (mfma_f32_16x16x32_bf16, A[m=lane&15][kk=quad*8+j]):
//   quad 0/1 : Linv_k[m][quad*8 + j]
//   quad 2   : j==0 -> -b_k[m]  (kk=16, pairs with B's bias-1 row), else 0
//   quad 3   : 0
__global__ __launch_bounds__(128) void prep_kernel(
    const float* __restrict__ mu, const float* __restrict__ sigma,
    const float* __restrict__ pi, float* __restrict__ ws)
{
    __shared__ float sLinv[KCOMP * DDIM * DDIM];
    __shared__ float sB[KCOMP * DDIM];
    __shared__ float sC[KCOMP];

    const int tid = threadIdx.x;
    const int g = tid >> 4;   // component
    const int r = tid & 15;   // row (cholesky) / column (inverse)

    float a[DDIM];
    const float4* srow = (const float4*)(sigma + g * DDIM * DDIM + r * DDIM);
    float4 v0 = srow[0], v1 = srow[1], v2 = srow[2], v3 = srow[3];
    a[0]=v0.x;  a[1]=v0.y;  a[2]=v0.z;  a[3]=v0.w;
    a[4]=v1.x;  a[5]=v1.y;  a[6]=v1.z;  a[7]=v1.w;
    a[8]=v2.x;  a[9]=v2.y;  a[10]=v2.z; a[11]=v2.w;
    a[12]=v3.x; a[13]=v3.y; a[14]=v3.z; a[15]=v3.w;

    // Cholesky: lane r computes row r of L via width-16 shuffles.
    float l[DDIM];
    #pragma unroll
    for (int j = 0; j < DDIM; ++j) {
        float s = a[j];
        #pragma unroll
        for (int m2 = 0; m2 < j; ++m2)
            s -= l[m2] * __shfl(l[m2], j, DDIM);
        float dj = sqrtf(__shfl(s, j, DDIM));
        float val;
        if (r == j)      val = dj;
        else if (r > j)  val = s / dj;
        else             val = 0.0f;
        l[j] = val;
    }

    // Invert L: lane r computes column r of Linv (forward substitution).
    float x[DDIM];
    #pragma unroll
    for (int i = 0; i < DDIM; ++i) {
        float t = (r == i) ? 1.0f : 0.0f;
        #pragma unroll
        for (int m2 = 0; m2 < i; ++m2)
            t -= __shfl(l[m2], i, DDIM) * x[m2];
        x[i] = t / __shfl(l[i], i, DDIM);
    }

    // Store Linv row-major: lane r holds column r -> element [i][r]
    #pragma unroll
    for (int i = 0; i < DDIM; ++i)
        sLinv[g * 256 + i * DDIM + r] = x[i];

    // b_r = sum_c Linv[r][c] * mu[c]  (same-wave LDS visibility)
    float b = 0.0f;
    #pragma unroll
    for (int c = 0; c < DDIM; ++c)
        b += sLinv[g * 256 + r * DDIM + c] * mu[g * DDIM + c];
    sB[g * DDIM + r] = b;

    // logdet = sum_r log(L_rr)
    float ld = logf(l[r]);
    #pragma unroll
    for (int off = 8; off >= 1; off >>= 1)
        ld += __shfl_xor(ld, off, DDIM);
    if (r == 0) {
        const float LOG2PI = 1.8378770664093454f;
        sC[g] = logf(pi[g]) - ld - 0.5f * DDIM * LOG2PI;
    }
    __syncthreads();

    // Emit the bf16 afrag table: 512 entries, 4 per thread.
    #pragma unroll
    for (int i = 0; i < 4; ++i) {
        const int e    = tid + i * 128;
        const int k    = e >> 6;
        const int lane = e & 63;
        const int m    = lane & 15;
        const int quad = lane >> 4;
        float vals[8];
        #pragma unroll
        for (int j = 0; j < 8; ++j) vals[j] = 0.0f;
        if (quad < 2) {
            #pragma unroll
            for (int j = 0; j < 8; ++j)
                vals[j] = sLinv[k * 256 + m * DDIM + quad * 8 + j];
        } else if (quad == 2) {
            vals[0] = -sB[k * DDIM + m];
        }
        uint4 p;
        p.x = (unsigned)f2bf(vals[0]) | ((unsigned)f2bf(vals[1]) << 16);
        p.y = (unsigned)f2bf(vals[2]) | ((unsigned)f2bf(vals[3]) << 16);
        p.z = (unsigned)f2bf(vals[4]) | ((unsigned)f2bf(vals[5]) << 16);
        p.w = (unsigned)f2bf(vals[6]) | ((unsigned)f2bf(vals[7]) << 16);
        ((uint4*)ws)[e] = p;
    }
    if (tid < KCOMP) ws[2048 + tid] = sC[tid];
}

// Scoring: one wave = 128 samples = 2 halves x 4 tiles of 16. A fragments
// straight from the prebuilt table (8 x dwordx4, L2-resident; amortized over
// 128 samples). B = z~^T per tile (z in quads 0/1 via truncating cvt,
// bf16(1.0) bias at kk=16 in quad 2). D: col=lane&15, row=quad*4+reg.
// maha broadcast via 2 shfl_xor; quad-select BEFORE the LSE -> each lane
// does one 8-way log-sum-exp per half for its own sample. No LDS, no scratch.
__global__ __launch_bounds__(256, 4) void energy_kernel(
    const float* __restrict__ z, const float* __restrict__ ws,
    float* __restrict__ out, int n)
{
    const int tid  = threadIdx.x;
    const int lane = tid & 63;
    const int m    = lane & 15;
    const int quad = lane >> 4;
    const int base = ((blockIdx.x * 256 + tid) >> 6) * 128;   // 128 samples/wave

    // A fragments: 8 x 16B loads, L2-resident
    bf16x8 afrag[KCOMP];
    #pragma unroll
    for (int k = 0; k < KCOMP; ++k)
        afrag[k] = ((const bf16x8*)ws)[k * 64 + lane];

    float ck[KCOMP];
    #pragma unroll
    for (int k = 0; k < KCOMP; ++k) ck[k] = ws[2048 + k];

    const f32x4 zero4 = {0.f, 0.f, 0.f, 0.f};

    // Two 64-sample halves; unroll 1 keeps register peak at the 4-tile level
    // (round-5 lesson: big live arrays -> scratch spills).
    #pragma unroll 1
    for (int half = 0; half < 2; ++half) {
        const int hb = base + half * 64;

        // Prefetch this half's 4 z-tiles; truncating fp32->bf16 (1 op/elem;
        // finite inputs can't become NaN; error far below tolerance).
        bf16x8 bfrag[4];
        #pragma unroll
        for (int t = 0; t < 4; ++t) {
            bf16x8 bf = {0,0,0,0,0,0,0,0};
            const int s = hb + t * 16 + m;
            if (quad < 2) {
                if (s < n) {
                    const float4* zp = (const float4*)(z + (size_t)s * DDIM + quad * 8);
                    float4 w0 = zp[0], w1 = zp[1];
                    bf[0]=(short)(__float_as_uint(w0.x) >> 16);
                    bf[1]=(short)(__float_as_uint(w0.y) >> 16);
                    bf[2]=(short)(__float_as_uint(w0.z) >> 16);
                    bf[3]=(short)(__float_as_uint(w0.w) >> 16);
                    bf[4]=(short)(__float_as_uint(w1.x) >> 16);
                    bf[5]=(short)(__float_as_uint(w1.y) >> 16);
                    bf[6]=(short)(__float_as_uint(w1.z) >> 16);
                    bf[7]=(short)(__float_as_uint(w1.w) >> 16);
                }
            } else if (quad == 2) {
                bf[0] = (short)0x3F80;   // bf16(1.0) bias row (kk = 16)
            }
            bfrag[t] = bf;
        }

        float lp[KCOMP];
        #pragma unroll
        for (int t = 0; t < 4; ++t) {
            #pragma unroll
            for (int k = 0; k < KCOMP; ++k) {
                f32x4 d4 = __builtin_amdgcn_mfma_f32_16x16x32_bf16(
                               afrag[k], bfrag[t], zero4, 0, 0, 0);
                float p = d4[0]*d4[0] + d4[1]*d4[1] + d4[2]*d4[2] + d4[3]*d4[3];
                p += __shfl_xor(p, 16, 64);
                p += __shfl_xor(p, 32, 64);     // all lanes: maha of tile t, col m
                float lpv = fmaf(-0.5f, p, ck[k]);
                if (t == 0) lp[k] = lpv;        // each lane keeps its quad's tile
                else        lp[k] = (quad == t) ? lpv : lp[k];
            }
        }

        // 8-component log-sum-exp for this lane's sample (hb + lane)
        float mx = lp[0];
        #pragma unroll
        for (int k = 1; k < KCOMP; ++k) mx = fmaxf(mx, lp[k]);
        float dens = 0.0f;
        #pragma unroll
        for (int k = 0; k < KCOMP; ++k) dens += __expf(lp[k] - mx);

        const int so = hb + lane;
        if (so < n) out[so] = -(mx + __logf(dens));
    }
}

extern "C" void kernel_launch(void* const* d_in, const int* in_sizes, int n_in,
                              void* d_out, int out_size, void* d_ws, size_t ws_size,
                              hipStream_t stream) {
    const float* mu    = (const float*)d_in[0];
    const float* sigma = (const float*)d_in[1];
    const float* z     = (const float*)d_in[2];
    const float* pi    = (const float*)d_in[3];
    float* ws  = (float*)d_ws;
    float* out = (float*)d_out;

    const int n = in_sizes[2] / DDIM;   // number of samples (524288)

    prep_kernel<<<1, 128, 0, stream>>>(mu, sigma, pi, ws);

    // 128 samples/wave, 4 waves/block -> 512 samples/block; 1024 blocks
    const int blocks = (n + 511) / 512;
    energy_kernel<<<blocks, 256, 0, stream>>>(z, ws, out, n);
}